// Round 2
// baseline (234.183 us; speedup 1.0000x reference)
//
#include <hip/hip_runtime.h>

// Problem constants (fixed by reference setup_inputs)
#define B_    8
#define C_    16
#define T_    2000
#define F_    128
#define F4_   32           // float4 per full feature row
#define POOL_ 10
#define T1_   200          // T_/POOL_ (exact, no tail)
#define BC_   128          // B_*C_
#define EPS_  1e-5f

#define G_      20         // pooled blocks per chunk
#define NCHUNK_ 10         // T1_/G_
#define QF4_    8          // float4 per 32-feature quarter row

// ---------------------------------------------------------------------------
// Fully fused causal instance-norm, occupancy-tuned.
// One WG per (bc, feature-quarter): grid = 128*4 = 512 WGs (2/CU),
// 320 threads (5 waves) -> 10 waves/CU (2.5/SIMD), vs 1/SIMD before.
// Thread (g,kp,f4): g=pooled block in chunk (0..19), kp=row parity, f4=quarter col.
// Per chunk: load 5 rows -> fold parity via shfl_xor(8) -> publish block sums
// to parity-double-buffered LDS -> ONE barrier -> causal prefix (j<=g, reads
// are same-address broadcasts) -> stats -> normalize held regs -> store.
// Next chunk's 5 loads issued before the barrier (latency hides under
// prefix/stats/store + the other resident waves).
// x read once (131 MB), out written once (131 MB), no workspace.
// ---------------------------------------------------------------------------
__global__ __launch_bounds__(320) void fused_cumnorm(
    const float4* __restrict__ x4, float4* __restrict__ out4)
{
    const int tid = (int)threadIdx.x;
    const int bc  = (int)blockIdx.x >> 2;
    const int q   = (int)blockIdx.x & 3;
    const int g   = tid >> 4;           // 0..19 : pooled block within chunk
    const int kp  = (tid >> 3) & 1;     // 0..1  : row parity within block
    const int f4  = tid & 7;            // 0..7  : float4 column within quarter

    __shared__ float4 sS  [2][G_][QF4_];   // per-chunk block sums (parity dbuf)
    __shared__ float4 sS2 [2][G_][QF4_];
    __shared__ float4 runS [2][QF4_];      // running totals (parity dbuf)
    __shared__ float4 runS2[2][QF4_];

    const size_t tbase = (size_t)bc * T_ * F4_ + (size_t)(g * POOL_ + kp) * F4_
                       + (size_t)q * QF4_ + (size_t)f4;
    const float4* __restrict__ pc = x4   + tbase;
    float4*       __restrict__ qc = out4 + tbase;

    const int RS = 2 * F4_;             // 64  : same-parity row stride
    const int CS = G_ * POOL_ * F4_;    // 6400: chunk stride

    // prologue: load chunk 0
    float4 v0 = pc[0], v1 = pc[RS], v2 = pc[2*RS], v3 = pc[3*RS], v4 = pc[4*RS];

    if (tid < QF4_) {
        runS [0][tid] = make_float4(0.f, 0.f, 0.f, 0.f);
        runS2[0][tid] = make_float4(0.f, 0.f, 0.f, 0.f);
    }
    // (visible after the first in-loop __syncthreads, before any read)

    for (int c = 0; c < NCHUNK_; ++c) {
        const int p = c & 1;

        // ---- partial block sums over this thread's 5 rows
        float4 s, s2;
        s.x = ((v0.x + v1.x) + (v2.x + v3.x)) + v4.x;
        s.y = ((v0.y + v1.y) + (v2.y + v3.y)) + v4.y;
        s.z = ((v0.z + v1.z) + (v2.z + v3.z)) + v4.z;
        s.w = ((v0.w + v1.w) + (v2.w + v3.w)) + v4.w;
        s2.x = v0.x*v0.x; s2.x = fmaf(v1.x,v1.x,s2.x); s2.x = fmaf(v2.x,v2.x,s2.x); s2.x = fmaf(v3.x,v3.x,s2.x); s2.x = fmaf(v4.x,v4.x,s2.x);
        s2.y = v0.y*v0.y; s2.y = fmaf(v1.y,v1.y,s2.y); s2.y = fmaf(v2.y,v2.y,s2.y); s2.y = fmaf(v3.y,v3.y,s2.y); s2.y = fmaf(v4.y,v4.y,s2.y);
        s2.z = v0.z*v0.z; s2.z = fmaf(v1.z,v1.z,s2.z); s2.z = fmaf(v2.z,v2.z,s2.z); s2.z = fmaf(v3.z,v3.z,s2.z); s2.z = fmaf(v4.z,v4.z,s2.z);
        s2.w = v0.w*v0.w; s2.w = fmaf(v1.w,v1.w,s2.w); s2.w = fmaf(v2.w,v2.w,s2.w); s2.w = fmaf(v3.w,v3.w,s2.w); s2.w = fmaf(v4.w,v4.w,s2.w);

        // ---- fold the kp pair (lanes l <-> l^8 within the wave)
        s.x  += __shfl_xor(s.x , 8);
        s.y  += __shfl_xor(s.y , 8);
        s.z  += __shfl_xor(s.z , 8);
        s.w  += __shfl_xor(s.w , 8);
        s2.x += __shfl_xor(s2.x, 8);
        s2.y += __shfl_xor(s2.y, 8);
        s2.z += __shfl_xor(s2.z, 8);
        s2.w += __shfl_xor(s2.w, 8);

        // ---- issue next chunk's loads early (hide HBM under prefix/stats/store)
        float4 w0, w1, w2, w3, w4;
        if (c + 1 < NCHUNK_) {
            const float4* pn = pc + CS;
            w0 = pn[0]; w1 = pn[RS]; w2 = pn[2*RS]; w3 = pn[3*RS]; w4 = pn[4*RS];
        } else {
            w0 = v0; w1 = v1; w2 = v2; w3 = v3; w4 = v4;
        }

        if (kp == 0) { sS[p][g][f4] = s; sS2[p][g][f4] = s2; }
        __syncthreads();   // sS[p] writes visible; runS[p] (prev iter / init) visible

        // ---- causal inclusive prefix over groups, seeded by running total
        float4 acc  = runS [p][f4];
        float4 acc2 = runS2[p][f4];
        for (int j = 0; j <= g; ++j) {
            float4 aj  = sS [p][j][f4];
            float4 a2j = sS2[p][j][f4];
            acc.x  += aj.x;  acc.y  += aj.y;  acc.z  += aj.z;  acc.w  += aj.w;
            acc2.x += a2j.x; acc2.y += a2j.y; acc2.z += a2j.z; acc2.w += a2j.w;
        }

        const float inv = 1.0f / (float)((c * G_ + g + 1) * POOL_);
        float4 mean, rstd;
        mean.x = acc.x * inv; rstd.x = rsqrtf(fmaf(-mean.x, mean.x, acc2.x * inv) + EPS_);
        mean.y = acc.y * inv; rstd.y = rsqrtf(fmaf(-mean.y, mean.y, acc2.y * inv) + EPS_);
        mean.z = acc.z * inv; rstd.z = rsqrtf(fmaf(-mean.z, mean.z, acc2.z * inv) + EPS_);
        mean.w = acc.w * inv; rstd.w = rsqrtf(fmaf(-mean.w, mean.w, acc2.w * inv) + EPS_);

        // ---- normalize held registers, store (same addresses as loads)
        float4 o;
        o.x = (v0.x - mean.x) * rstd.x; o.y = (v0.y - mean.y) * rstd.y;
        o.z = (v0.z - mean.z) * rstd.z; o.w = (v0.w - mean.w) * rstd.w;
        qc[0] = o;
        o.x = (v1.x - mean.x) * rstd.x; o.y = (v1.y - mean.y) * rstd.y;
        o.z = (v1.z - mean.z) * rstd.z; o.w = (v1.w - mean.w) * rstd.w;
        qc[RS] = o;
        o.x = (v2.x - mean.x) * rstd.x; o.y = (v2.y - mean.y) * rstd.y;
        o.z = (v2.z - mean.z) * rstd.z; o.w = (v2.w - mean.w) * rstd.w;
        qc[2*RS] = o;
        o.x = (v3.x - mean.x) * rstd.x; o.y = (v3.y - mean.y) * rstd.y;
        o.z = (v3.z - mean.z) * rstd.z; o.w = (v3.w - mean.w) * rstd.w;
        qc[3*RS] = o;
        o.x = (v4.x - mean.x) * rstd.x; o.y = (v4.y - mean.y) * rstd.y;
        o.z = (v4.z - mean.z) * rstd.z; o.w = (v4.w - mean.w) * rstd.w;
        qc[4*RS] = o;

        // ---- group G-1's inclusive prefix IS the next running total
        if (g == G_ - 1 && kp == 0) {
            runS [p ^ 1][f4] = acc;
            runS2[p ^ 1][f4] = acc2;
        }
        // no second barrier: next iter writes sS[p^1] (disjoint), and the
        // runS[p^1] read happens after the NEXT iteration's __syncthreads.

        v0 = w0; v1 = w1; v2 = w2; v3 = w3; v4 = w4;
        pc += CS; qc += CS;
    }
}

extern "C" void kernel_launch(void* const* d_in, const int* in_sizes, int n_in,
                              void* d_out, int out_size, void* d_ws, size_t ws_size,
                              hipStream_t stream)
{
    (void)in_sizes; (void)n_in; (void)d_ws; (void)ws_size; (void)out_size;
    // 128 bc x 4 feature-quarters = 512 WGs (2/CU), 320 threads (5 waves)
    // -> 10 waves/CU resident, one barrier per 20-block chunk.
    fused_cumnorm<<<BC_ * 4, 320, 0, stream>>>(
        (const float4*)d_in[0], (float4*)d_out);
}

// Round 3
// 232.907 us; speedup vs baseline: 1.0055x; 1.0055x over previous
//
#include <hip/hip_runtime.h>

// Problem constants (fixed by reference setup_inputs)
#define B_    8
#define C_    16
#define T_    2000
#define F_    128
#define F4_   32           // float4 per full feature row
#define POOL_ 10
#define T1_   200          // T_/POOL_ (exact, no tail)
#define BC_   128          // B_*C_
#define EPS_  1e-5f

#define G_      20         // pooled blocks per chunk
#define NCHUNK_ 10         // T1_/G_
#define QF4_    8          // float4 per 32-feature quarter row

// ---------------------------------------------------------------------------
// Barrier that orders LDS traffic only: drains lgkmcnt, NOT vmcnt, so the
// global prefetch loads (and streaming stores) stay in flight across it.
// __syncthreads() would emit s_waitcnt vmcnt(0) and serialize every chunk on
// a full HBM round-trip (the round-2 bottleneck: ~2.3 KB avg in-flight/CU
// vs ~9 KB needed by Little's law).
// sched_barrier(0) fences compiler reordering around the asm (rule #18).
// ---------------------------------------------------------------------------
static __device__ __forceinline__ void wg_barrier_lds_only()
{
    __builtin_amdgcn_sched_barrier(0);
    asm volatile("s_waitcnt lgkmcnt(0)\n\ts_barrier" ::: "memory");
    __builtin_amdgcn_sched_barrier(0);
}

// ---------------------------------------------------------------------------
// Fully fused causal instance-norm. One WG per (bc, feature-quarter):
// grid = 128*4 = 512 WGs (2/CU), 320 threads (5 waves) -> 10 waves/CU.
// Thread (g,kp,f4): g=pooled block in chunk (0..19), kp=row parity, f4=col.
// Per chunk: load 5 rows -> fold parity via shfl_xor(8) -> publish block sums
// to parity-double-buffered LDS -> LDS-only barrier -> causal prefix (j<=g,
// same-address broadcast reads) -> stats -> normalize held regs -> store.
// Next chunk's 5 loads are issued before the barrier and REMAIN IN FLIGHT
// across it; they are waited only at first register use next iteration.
// x read once (131 MB), out written once (131 MB), no workspace.
// ---------------------------------------------------------------------------
__global__ __launch_bounds__(320) void fused_cumnorm(
    const float4* __restrict__ x4, float4* __restrict__ out4)
{
    const int tid = (int)threadIdx.x;
    const int bc  = (int)blockIdx.x >> 2;
    const int q   = (int)blockIdx.x & 3;
    const int g   = tid >> 4;           // 0..19 : pooled block within chunk
    const int kp  = (tid >> 3) & 1;     // 0..1  : row parity within block
    const int f4  = tid & 7;            // 0..7  : float4 column within quarter

    __shared__ float4 sS  [2][G_][QF4_];   // per-chunk block sums (parity dbuf)
    __shared__ float4 sS2 [2][G_][QF4_];
    __shared__ float4 runS [2][QF4_];      // running totals (parity dbuf)
    __shared__ float4 runS2[2][QF4_];

    const size_t tbase = (size_t)bc * T_ * F4_ + (size_t)(g * POOL_ + kp) * F4_
                       + (size_t)q * QF4_ + (size_t)f4;
    const float4* __restrict__ pc = x4   + tbase;
    float4*       __restrict__ qc = out4 + tbase;

    const int RS = 2 * F4_;             // 64  : same-parity row stride
    const int CS = G_ * POOL_ * F4_;    // 6400: chunk stride

    // prologue: load chunk 0
    float4 v0 = pc[0], v1 = pc[RS], v2 = pc[2*RS], v3 = pc[3*RS], v4 = pc[4*RS];

    if (tid < QF4_) {
        runS [0][tid] = make_float4(0.f, 0.f, 0.f, 0.f);
        runS2[0][tid] = make_float4(0.f, 0.f, 0.f, 0.f);
    }
    // (visible after the first in-loop barrier, before any read)

    for (int c = 0; c < NCHUNK_; ++c) {
        const int p = c & 1;

        // ---- partial block sums over this thread's 5 rows
        float4 s, s2;
        s.x = ((v0.x + v1.x) + (v2.x + v3.x)) + v4.x;
        s.y = ((v0.y + v1.y) + (v2.y + v3.y)) + v4.y;
        s.z = ((v0.z + v1.z) + (v2.z + v3.z)) + v4.z;
        s.w = ((v0.w + v1.w) + (v2.w + v3.w)) + v4.w;
        s2.x = v0.x*v0.x; s2.x = fmaf(v1.x,v1.x,s2.x); s2.x = fmaf(v2.x,v2.x,s2.x); s2.x = fmaf(v3.x,v3.x,s2.x); s2.x = fmaf(v4.x,v4.x,s2.x);
        s2.y = v0.y*v0.y; s2.y = fmaf(v1.y,v1.y,s2.y); s2.y = fmaf(v2.y,v2.y,s2.y); s2.y = fmaf(v3.y,v3.y,s2.y); s2.y = fmaf(v4.y,v4.y,s2.y);
        s2.z = v0.z*v0.z; s2.z = fmaf(v1.z,v1.z,s2.z); s2.z = fmaf(v2.z,v2.z,s2.z); s2.z = fmaf(v3.z,v3.z,s2.z); s2.z = fmaf(v4.z,v4.z,s2.z);
        s2.w = v0.w*v0.w; s2.w = fmaf(v1.w,v1.w,s2.w); s2.w = fmaf(v2.w,v2.w,s2.w); s2.w = fmaf(v3.w,v3.w,s2.w); s2.w = fmaf(v4.w,v4.w,s2.w);

        // ---- fold the kp pair (lanes l <-> l^8 within the wave)
        s.x  += __shfl_xor(s.x , 8);
        s.y  += __shfl_xor(s.y , 8);
        s.z  += __shfl_xor(s.z , 8);
        s.w  += __shfl_xor(s.w , 8);
        s2.x += __shfl_xor(s2.x, 8);
        s2.y += __shfl_xor(s2.y, 8);
        s2.z += __shfl_xor(s2.z, 8);
        s2.w += __shfl_xor(s2.w, 8);

        // ---- publish block sums (starts the lgkmcnt clock early)
        if (kp == 0) { sS[p][g][f4] = s; sS2[p][g][f4] = s2; }

        // ---- issue next chunk's loads; they stay in flight across the barrier
        float4 w0, w1, w2, w3, w4;
        if (c + 1 < NCHUNK_) {
            const float4* pn = pc + CS;
            w0 = pn[0]; w1 = pn[RS]; w2 = pn[2*RS]; w3 = pn[3*RS]; w4 = pn[4*RS];
        } else {
            w0 = v0; w1 = v1; w2 = v2; w3 = v3; w4 = v4;
        }

        wg_barrier_lds_only();   // LDS visibility only; vmem NOT drained

        // ---- causal inclusive prefix over groups, seeded by running total
        float4 acc  = runS [p][f4];
        float4 acc2 = runS2[p][f4];
        for (int j = 0; j <= g; ++j) {
            float4 aj  = sS [p][j][f4];
            float4 a2j = sS2[p][j][f4];
            acc.x  += aj.x;  acc.y  += aj.y;  acc.z  += aj.z;  acc.w  += aj.w;
            acc2.x += a2j.x; acc2.y += a2j.y; acc2.z += a2j.z; acc2.w += a2j.w;
        }

        const float inv = 1.0f / (float)((c * G_ + g + 1) * POOL_);
        float4 mean, rstd;
        mean.x = acc.x * inv; rstd.x = rsqrtf(fmaf(-mean.x, mean.x, acc2.x * inv) + EPS_);
        mean.y = acc.y * inv; rstd.y = rsqrtf(fmaf(-mean.y, mean.y, acc2.y * inv) + EPS_);
        mean.z = acc.z * inv; rstd.z = rsqrtf(fmaf(-mean.z, mean.z, acc2.z * inv) + EPS_);
        mean.w = acc.w * inv; rstd.w = rsqrtf(fmaf(-mean.w, mean.w, acc2.w * inv) + EPS_);

        // ---- normalize held registers, store (same addresses as loads)
        float4 o;
        o.x = (v0.x - mean.x) * rstd.x; o.y = (v0.y - mean.y) * rstd.y;
        o.z = (v0.z - mean.z) * rstd.z; o.w = (v0.w - mean.w) * rstd.w;
        qc[0] = o;
        o.x = (v1.x - mean.x) * rstd.x; o.y = (v1.y - mean.y) * rstd.y;
        o.z = (v1.z - mean.z) * rstd.z; o.w = (v1.w - mean.w) * rstd.w;
        qc[RS] = o;
        o.x = (v2.x - mean.x) * rstd.x; o.y = (v2.y - mean.y) * rstd.y;
        o.z = (v2.z - mean.z) * rstd.z; o.w = (v2.w - mean.w) * rstd.w;
        qc[2*RS] = o;
        o.x = (v3.x - mean.x) * rstd.x; o.y = (v3.y - mean.y) * rstd.y;
        o.z = (v3.z - mean.z) * rstd.z; o.w = (v3.w - mean.w) * rstd.w;
        qc[3*RS] = o;
        o.x = (v4.x - mean.x) * rstd.x; o.y = (v4.y - mean.y) * rstd.y;
        o.z = (v4.z - mean.z) * rstd.z; o.w = (v4.w - mean.w) * rstd.w;
        qc[4*RS] = o;

        // ---- group G-1's inclusive prefix IS the next running total
        if (g == G_ - 1 && kp == 0) {
            runS [p ^ 1][f4] = acc;
            runS2[p ^ 1][f4] = acc2;
        }
        // no second barrier: next iter writes sS[p^1] (disjoint), and the
        // runS[p^1] read happens after the NEXT iteration's barrier.

        v0 = w0; v1 = w1; v2 = w2; v3 = w3; v4 = w4;
        pc += CS; qc += CS;
    }
}

extern "C" void kernel_launch(void* const* d_in, const int* in_sizes, int n_in,
                              void* d_out, int out_size, void* d_ws, size_t ws_size,
                              hipStream_t stream)
{
    (void)in_sizes; (void)n_in; (void)d_ws; (void)ws_size; (void)out_size;
    // 128 bc x 4 feature-quarters = 512 WGs (2/CU), 320 threads (5 waves)
    // -> 10 waves/CU resident; one LDS-only barrier per 20-block chunk.
    fused_cumnorm<<<BC_ * 4, 320, 0, stream>>>(
        (const float4*)d_in[0], (float4*)d_out);
}